// Round 1
// 338.141 us; speedup vs baseline: 1.0024x; 1.0024x over previous
//
#include <hip/hip_runtime.h>
#include <hip/hip_bf16.h>
#include <math.h>

typedef __hip_bfloat16 bf16;
typedef __attribute__((ext_vector_type(8))) short short8;   // 8 bf16 = 4 VGPRs
typedef __attribute__((ext_vector_type(4))) short s4v;      // 4 bf16 = 8 B
typedef __attribute__((ext_vector_type(4))) float f32x4;    // MFMA acc

__device__ __forceinline__ float ldf(const float* p, size_t i) { return p[i]; }
__device__ __forceinline__ float ldf(const bf16*  p, size_t i) { return __bfloat162float(p[i]); }
__device__ __forceinline__ void  stf(float* p, size_t i, float v) { p[i] = v; }
__device__ __forceinline__ void  stf(bf16*  p, size_t i, float v) { p[i] = __float2bfloat16(v); }

__device__ __forceinline__ float ex2(float x) { return __builtin_amdgcn_exp2f(x); }

// async global->LDS, 16 B per lane; dest = wave-uniform base + lane*16 (m97/m104)
__device__ __forceinline__ void gl16(const void* gp, void* lp) {
    __builtin_amdgcn_global_load_lds(
        (const __attribute__((address_space(1))) void*)gp,
        (__attribute__((address_space(3))) void*)lp, 16, 0, 0);
}

// ---------------------------------------------------------------------------
// fp32 -> bf16 convert (grid-stride)
// ---------------------------------------------------------------------------
__global__ __launch_bounds__(256) void cvt_kernel(
    const float* __restrict__ src, bf16* __restrict__ dst, int n)
{
    for (int i = blockIdx.x * 256 + threadIdx.x; i < n; i += gridDim.x * 256)
        dst[i] = __float2bfloat16(src[i]);
}

// all 6 weight matrices -> one contiguous bf16 region (4,194,304 elems)
__global__ __launch_bounds__(256) void cvt_w(
    const float* __restrict__ s0, const float* __restrict__ s1,
    const float* __restrict__ s2, const float* __restrict__ s3,
    const float* __restrict__ s4, const float* __restrict__ s5,
    bf16* __restrict__ dst)
{
    int i = blockIdx.x * 256 + threadIdx.x;
    const float* s; int off;
    if      (i <  786432) { s = s0; off = 0; }
    else if (i < 1048576) { s = s1; off =  786432; }
    else if (i < 1835008) { s = s2; off = 1048576; }
    else if (i < 2097152) { s = s3; off = 1835008; }
    else if (i < 3145728) { s = s4; off = 2097152; }
    else                  { s = s5; off = 3145728; }
    dst[i] = __float2bfloat16(s[i - off]);
}

// ---------------------------------------------------------------------------
// MFMA GEMM: BM=BN=128, BK=64, XOR-swizzled LDS (group g at g^(row&7)) +
// double-buffered async global_load_lds prefetch. 4 waves (2x2), 64x64/wave.
// C[M,N] = act(A[M,K] @ W[N,K]^T + bias[N]); EPI: 0=none, 1=exact GELU.
// ---------------------------------------------------------------------------
template <int EPI>
__global__ __launch_bounds__(256) void gemm_mfma(
    const bf16* __restrict__ A, const bf16* __restrict__ W,
    const float* __restrict__ bias, bf16* __restrict__ C,
    int M, int N, int K)
{
    __shared__ __align__(16) bf16 Asl[2][128 * 64];
    __shared__ __align__(16) bf16 Bsl[2][128 * 64];

    const int tid  = threadIdx.x;
    const int lane = tid & 63;
    const int wave = tid >> 6;
    const int wm   = wave >> 1;
    const int wn   = wave & 1;
    const int l15  = lane & 15;
    const int quad = lane >> 4;
    const int sr   = lane >> 3;                 // staging row within 8
    const int sc   = ((lane & 7) ^ sr) * 8;     // swizzled source column

    const int row0 = blockIdx.y * 128, col0 = blockIdx.x * 128;

    f32x4 acc[4][4] = {};

    const int nk = K >> 6;

    // prologue: stage tile 0 -> buf 0
    #pragma unroll
    for (int t = 0; t < 4; t++) {
        int r0 = wave * 32 + t * 8;             // wave-uniform, multiple of 8
        gl16(&A[(size_t)(row0 + r0 + sr) * K + sc], &Asl[0][r0 * 64]);
        gl16(&W[(size_t)(col0 + r0 + sr) * K + sc], &Bsl[0][r0 * 64]);
    }

    int cur = 0;
    for (int i = 0; i < nk; i++) {
        __syncthreads();   // drains vmcnt for buf[cur]; prior reads of buf[cur^1] done
        if (i + 1 < nk) {
            int k1 = (i + 1) << 6;
            #pragma unroll
            for (int t = 0; t < 4; t++) {
                int r0 = wave * 32 + t * 8;
                gl16(&A[(size_t)(row0 + r0 + sr) * K + k1 + sc], &Asl[cur ^ 1][r0 * 64]);
                gl16(&W[(size_t)(col0 + r0 + sr) * K + k1 + sc], &Bsl[cur ^ 1][r0 * 64]);
            }
        }

        #pragma unroll
        for (int ks = 0; ks < 64; ks += 32) {
            short8 af[4], bfr[4];
            const int g0 = (ks >> 3) + quad;
            const int col = (g0 ^ (l15 & 7)) * 8;   // un-swizzle on read
            #pragma unroll
            for (int mt = 0; mt < 4; mt++)
                af[mt] = *(const short8*)&Asl[cur][(wm * 64 + mt * 16 + l15) * 64 + col];
            #pragma unroll
            for (int nt = 0; nt < 4; nt++)
                bfr[nt] = *(const short8*)&Bsl[cur][(wn * 64 + nt * 16 + l15) * 64 + col];
            #pragma unroll
            for (int mt = 0; mt < 4; mt++)
                #pragma unroll
                for (int nt = 0; nt < 4; nt++)
                    acc[mt][nt] = __builtin_amdgcn_mfma_f32_16x16x32_bf16(
                        af[mt], bfr[nt], acc[mt][nt], 0, 0, 0);
        }
        cur ^= 1;
    }

    #pragma unroll
    for (int mt = 0; mt < 4; mt++) {
        int row = row0 + wm * 64 + mt * 16 + quad * 4;
        #pragma unroll
        for (int nt = 0; nt < 4; nt++) {
            int col = col0 + wn * 64 + nt * 16 + l15;
            float bv = bias[col];
            #pragma unroll
            for (int r = 0; r < 4; r++) {
                float v = acc[mt][nt][r] + bv;
                if (EPI == 1) v = 0.5f * v * (1.0f + erff(v * 0.70710678118654752f));
                C[(size_t)(row + r) * N + col] = __float2bfloat16(v);
            }
        }
    }
}

// ---------------------------------------------------------------------------
// MFMA flash attention, v2 (latency-focused rework):
//  - 1 q-sub-tile per wave (64 q rows/block) -> 2x block count, 4 blocks/CU
//  - single K/V LDS buffer; global->reg loads for tile i+1 issued before the
//    compute phase of tile i (T14 async-STAGE split), written after barrier
//  - V staged with 8B vector loads + 4-row-packed b64 LDS writes (stride 68:
//    conflict-free writes AND reads, 8B-aligned)
//  - defer-rescale (THR=8 in log2 domain): skip max-update/acc-rescale unless
//    __any(cm2 > m2+8); alpha / 1/l broadcast via shfl (aX LDS removed)
//  - bijective XCD-chunked block swizzle: all q-blocks of one (b,h) pair on
//    one XCD -> K/V (256KB/pair, 2MB/XCD) stays L2-resident
// LQ: log2(#k-tiles) = log2(S/64). Grid: 64<<LQ blocks of 256 threads.
// ---------------------------------------------------------------------------
template <int LQ>
__global__ __launch_bounds__(256) void flash_attn_mfma(
    const bf16* __restrict__ qkv, bf16* __restrict__ o)
{
    __shared__ __align__(16) bf16 Ks[64 * 72];
    __shared__ __align__(16) bf16 Vt[64 * 68];
    __shared__ __align__(16) bf16 Pl[4][16 * 72];

    const int S   = 64 << LQ;
    const int nQB = 1 << LQ;

    const int tid  = threadIdx.x;
    const int wave = tid >> 6, lane = tid & 63;
    const int l15  = lane & 15, quad = lane >> 4;

    // XCD-chunked swizzle (grid = 64<<LQ, divisible by 8 -> bijective)
    const int r    = blockIdx.x;
    const int w    = (r & 7) * (8 << LQ) + (r >> 3);
    const int qblk = w & (nQB - 1);
    const int bh   = w >> LQ;
    const int h    = bh & 7, bb = bh >> 3;
    const int q0   = qblk * 64;

    const bf16* base = qkv + (size_t)bb * S * 1536 + h * 64;

    // Q fragments for this wave's 16 rows
    short8 qf[2];
    {
        size_t qoff = (size_t)(q0 + wave * 16 + l15) * 1536;
        qf[0] = *(const short8*)&base[qoff + quad * 8];
        qf[1] = *(const short8*)&base[qoff + 32 + quad * 8];
    }

    f32x4 oacc[4] = {};
    float m2 = -3.0e38f, lrow = 0.f;
    const float CE = 0.18033688f;   // 0.125 * log2(e)

    // staging registers (tile i+1 in flight while tile i computes)
    short8 kst[2];
    s4v    vst[4];
    const int vr4 = (tid >> 4) * 4;        // 4-row group   [0,64)
    const int vc0 = (tid & 15) * 4;        // 4-col group   [0,64)

    auto LOADK = [&](int k0) {
        #pragma unroll
        for (int t = 0; t < 2; t++) {
            int c = tid + 256 * t;
            int rr = c >> 3, col = (c & 7) * 8;
            kst[t] = *(const short8*)&base[(size_t)(k0 + rr) * 1536 + 512 + col];
        }
        #pragma unroll
        for (int rr = 0; rr < 4; rr++)
            vst[rr] = *(const s4v*)&base[(size_t)(k0 + vr4 + rr) * 1536 + 1024 + vc0];
    };

    auto WRITEKV = [&]() {
        #pragma unroll
        for (int t = 0; t < 2; t++) {
            int c = tid + 256 * t;
            int rr = c >> 3, col = (c & 7) * 8;
            *(short8*)&Ks[rr * 72 + col] = kst[t];
        }
        // Vt[d][k] (transposed), stride 68: pack rows (k) pairwise -> b64 writes
        #pragma unroll
        for (int i = 0; i < 4; i++) {
            union { bf16 b[4]; unsigned u[2]; } pk;
            pk.b[0] = ((const bf16*)&vst[0])[i];
            pk.b[1] = ((const bf16*)&vst[1])[i];
            pk.b[2] = ((const bf16*)&vst[2])[i];
            pk.b[3] = ((const bf16*)&vst[3])[i];
            *(unsigned long long*)&Vt[(vc0 + i) * 68 + vr4] =
                *(const unsigned long long*)pk.u;
        }
    };

    LOADK(0);
    const int nt = 1 << LQ;
    for (int it = 0; it < nt; it++) {
        __syncthreads();                    // all waves done reading Ks/Vt
        WRITEKV();                          // vmcnt-waits on kst/vst here
        __syncthreads();                    // staged tile visible
        if (it + 1 < nt) LOADK((it + 1) << 6);   // overlaps compute below

        // S^T = K @ Q^T  (lane holds S^T[k = mt*16+quad*4+r][q = l15])
        f32x4 st[4] = {};
        #pragma unroll
        for (int mt = 0; mt < 4; mt++) {
            short8 kf0 = *(const short8*)&Ks[(mt * 16 + l15) * 72 + quad * 8];
            short8 kf1 = *(const short8*)&Ks[(mt * 16 + l15) * 72 + 32 + quad * 8];
            st[mt] = __builtin_amdgcn_mfma_f32_16x16x32_bf16(kf0, qf[0], st[mt], 0, 0, 0);
            st[mt] = __builtin_amdgcn_mfma_f32_16x16x32_bf16(kf1, qf[1], st[mt], 0, 0, 0);
        }

        // row max (per q-row l15, uniform across quads after xor-reduce)
        float cm = -3.0e38f;
        #pragma unroll
        for (int mt = 0; mt < 4; mt++)
            #pragma unroll
            for (int rr = 0; rr < 4; rr++) cm = fmaxf(cm, st[mt][rr]);
        cm = fmaxf(cm, __shfl_xor(cm, 16));
        cm = fmaxf(cm, __shfl_xor(cm, 32));
        float cm2 = cm * CE;

        // defer-rescale: only pay the O-rescale when max grew by > 8 (log2)
        if (__any(cm2 > m2 + 8.f)) {
            float mn2   = fmaxf(m2, cm2);
            float alpha = ex2(m2 - mn2);
            m2 = mn2;
            lrow *= alpha;
            float a4[4];
            #pragma unroll
            for (int rr = 0; rr < 4; rr++) a4[rr] = __shfl(alpha, quad * 4 + rr);
            #pragma unroll
            for (int ntt = 0; ntt < 4; ntt++)
                #pragma unroll
                for (int rr = 0; rr < 4; rr++) oacc[ntt][rr] *= a4[rr];
        }

        // P = exp2(st*CE - m2)  (bounded by 2^8), pack to bf16 in Pl
        float ps = 0.f;
        #pragma unroll
        for (int mt = 0; mt < 4; mt++) {
            s4v pw;
            #pragma unroll
            for (int rr = 0; rr < 4; rr++) {
                float p = ex2(st[mt][rr] * CE - m2);
                ps += p;
                union { bf16 b; short hh; } cv;
                cv.b = __float2bfloat16(p);
                pw[rr] = cv.hh;
            }
            *(s4v*)&Pl[wave][l15 * 72 + mt * 16 + quad * 4] = pw;
        }
        ps += __shfl_xor(ps, 16);
        ps += __shfl_xor(ps, 32);
        lrow += ps;

        // O += P @ V   (A-frag from Pl, B-frag from Vt)
        #pragma unroll
        for (int kb = 0; kb < 2; kb++) {
            short8 pf = *(const short8*)&Pl[wave][l15 * 72 + kb * 32 + quad * 8];
            #pragma unroll
            for (int ntt = 0; ntt < 4; ntt++) {
                const bf16* vp = &Vt[(ntt * 16 + l15) * 68 + kb * 32 + quad * 8];
                short8 vf;
                *(unsigned long long*)&vf       = *(const unsigned long long*)vp;
                *((unsigned long long*)&vf + 1) = *(const unsigned long long*)(vp + 4);
                oacc[ntt] = __builtin_amdgcn_mfma_f32_16x16x32_bf16(pf, vf, oacc[ntt], 0, 0, 0);
            }
        }
    }

    // epilogue: normalize by 1/l (broadcast per acc row via shfl) and store
    float inv = 1.0f / lrow;
    float iv[4];
    #pragma unroll
    for (int rr = 0; rr < 4; rr++) iv[rr] = __shfl(inv, quad * 4 + rr);
    #pragma unroll
    for (int ntt = 0; ntt < 4; ntt++)
        #pragma unroll
        for (int rr = 0; rr < 4; rr++) {
            size_t row = (size_t)bb * S + q0 + wave * 16 + quad * 4 + rr;
            o[row * 512 + h * 64 + ntt * 16 + l15] = __float2bfloat16(oacc[ntt][rr] * iv[rr]);
        }
}

// ---------------------------------------------------------------------------
// out = LN(a + b) * g + beta over D=512. One block (256 thr) per row.
// ---------------------------------------------------------------------------
template <typename AT, typename OT, bool INTERP>
__global__ __launch_bounds__(256) void ln_kernel(
    const AT* __restrict__ a, const bf16* __restrict__ bsrc,
    const float* __restrict__ g, const float* __restrict__ beta,
    OT* __restrict__ out)
{
    const int row = blockIdx.x;
    const int t = threadIdx.x;
    const size_t base = (size_t)row * 512;

    float a0 = ldf(a, base + t), a1 = ldf(a, base + t + 256);
    float b0, b1;
    if (INTERP) {
        int s = row & 1023, bb = row >> 10;
        float src = fminf(fmaxf((s + 0.5f) * 0.5f - 0.5f, 0.f), 511.f);
        int i0 = (int)src;
        int i1 = min(i0 + 1, 511);
        float w = src - (float)i0;
        size_t r0 = ((size_t)bb * 512 + i0) * 512;
        size_t r1 = ((size_t)bb * 512 + i1) * 512;
        b0 = __bfloat162float(bsrc[r0 + t]) * (1.f - w) + __bfloat162float(bsrc[r1 + t]) * w;
        b1 = __bfloat162float(bsrc[r0 + t + 256]) * (1.f - w) + __bfloat162float(bsrc[r1 + t + 256]) * w;
    } else {
        b0 = __bfloat162float(bsrc[base + t]);
        b1 = __bfloat162float(bsrc[base + t + 256]);
    }
    float v0 = a0 + b0, v1 = a1 + b1;

    __shared__ float red[4];
    const int lane = t & 63, wid = t >> 6;

    float sm = v0 + v1;
    #pragma unroll
    for (int off = 32; off > 0; off >>= 1) sm += __shfl_xor(sm, off);
    if (lane == 0) red[wid] = sm;
    __syncthreads();
    sm = red[0] + red[1] + red[2] + red[3];
    const float mean = sm * (1.0f / 512.0f);

    float d0 = v0 - mean, d1 = v1 - mean;
    float vv = d0 * d0 + d1 * d1;
    __syncthreads();
    #pragma unroll
    for (int off = 32; off > 0; off >>= 1) vv += __shfl_xor(vv, off);
    if (lane == 0) red[wid] = vv;
    __syncthreads();
    vv = red[0] + red[1] + red[2] + red[3];
    const float rstd = rsqrtf(vv * (1.0f / 512.0f) + 1e-5f);

    stf(out, base + t,       d0 * rstd * g[t]       + beta[t]);
    stf(out, base + t + 256, d1 * rstd * g[t + 256] + beta[t + 256]);
}

// ---------------------------------------------------------------------------
// avg_pool1d k=2 s=2 along S: [B,1024,512] -> [B,512,512]  (bf16)
// ---------------------------------------------------------------------------
__global__ __launch_bounds__(256) void pool_kernel(
    const bf16* __restrict__ x, bf16* __restrict__ p)
{
    size_t i = (size_t)blockIdx.x * 256 + threadIdx.x;
    size_t d = i & 511;
    size_t rs = i >> 9;
    size_t b = rs >> 9, s = rs & 511;
    size_t r = (b * 1024 + 2 * s) * 512 + d;
    p[i] = __float2bfloat16(0.5f * (__bfloat162float(x[r]) + __bfloat162float(x[r + 512])));
}

// ---------------------------------------------------------------------------
// launch
// ---------------------------------------------------------------------------
extern "C" void kernel_launch(void* const* d_in, const int* in_sizes, int n_in,
                              void* d_out, int out_size, void* d_ws, size_t ws_size,
                              hipStream_t stream)
{
    const float* x      = (const float*)d_in[0];
    const float* w_in1  = (const float*)d_in[1];
    const float* b_in1  = (const float*)d_in[2];
    const float* w_out1 = (const float*)d_in[3];
    const float* b_out1 = (const float*)d_in[4];
    const float* w_in2  = (const float*)d_in[5];
    const float* b_in2  = (const float*)d_in[6];
    const float* w_out2 = (const float*)d_in[7];
    const float* b_out2 = (const float*)d_in[8];
    const float* g1     = (const float*)d_in[9];
    const float* be1    = (const float*)d_in[10];
    const float* g2     = (const float*)d_in[11];
    const float* be2    = (const float*)d_in[12];
    const float* g3     = (const float*)d_in[13];
    const float* be3    = (const float*)d_in[14];
    const float* w_ff1  = (const float*)d_in[15];
    const float* b_ff1  = (const float*)d_in[16];
    const float* w_ff2  = (const float*)d_in[17];
    const float* b_ff2  = (const float*)d_in[18];

    // workspace: bf16 elements; peak 50,331,648 elems = 100.66 MB (proven size)
    bf16* ws     = (bf16*)d_ws;
    bf16* xb     = ws + 0;            // [8,1024, 512]
    bf16* wq1    = ws + 4194304;      // [1536,512]   -- weights contiguous:
    bf16* wo1    = ws + 4980736;      // [512,512]
    bf16* wq2    = ws + 5242880;      // [1536,512]
    bf16* wo2    = ws + 6029312;      // [512,512]
    bf16* wf1    = ws + 6291456;      // [2048,512]
    bf16* wf2    = ws + 7340032;      // [512,2048]
    bf16* qkv1   = ws + 8388608;      // [8,1024,1536]
    bf16* o1     = ws + 20971520;     // [8,1024, 512]
    bf16* a1     = ws + 25165824;     // [8,1024, 512]
    bf16* x1     = ws + 29360128;     // [8,1024, 512]
    bf16* pooled = ws + 33554432;     // [8, 512, 512]
    bf16* qkv2   = ws + 35651584;     // [8, 512,1536]
    bf16* o2     = ws + 41943040;     // [8, 512, 512]
    bf16* a2     = ws + 44040192;     // [8, 512, 512]
    bf16* x2     = ws + 46137344;     // [8,1024, 512]
    bf16* h      = ws + 8388608;      // [8,1024,2048] (qkv1/o1 dead)
    bf16* ff     = ws + 25165824;     // [8,1024, 512] (a1 dead)

    dim3 blk(256);

    cvt_kernel<<<4096, blk, 0, stream>>>(x, xb, 4194304);
    cvt_w<<<16384, blk, 0, stream>>>(w_in1, w_out1, w_in2, w_out2, w_ff1, w_ff2, wq1);

    gemm_mfma<0><<<dim3(12, 64), blk, 0, stream>>>(xb, wq1, b_in1, qkv1, 8192, 1536, 512);
    flash_attn_mfma<4><<<dim3(1024), blk, 0, stream>>>(qkv1, o1);
    gemm_mfma<0><<<dim3(4, 64), blk, 0, stream>>>(o1, wo1, b_out1, a1, 8192, 512, 512);
    ln_kernel<float, bf16, false><<<8192, blk, 0, stream>>>(x, a1, g1, be1, x1);
    pool_kernel<<<8192, blk, 0, stream>>>(x1, pooled);
    gemm_mfma<0><<<dim3(12, 32), blk, 0, stream>>>(pooled, wq2, b_in2, qkv2, 4096, 1536, 512);
    flash_attn_mfma<3><<<dim3(512), blk, 0, stream>>>(qkv2, o2);
    gemm_mfma<0><<<dim3(4, 32), blk, 0, stream>>>(o2, wo2, b_out2, a2, 4096, 512, 512);
    ln_kernel<bf16, bf16, true><<<8192, blk, 0, stream>>>(x1, a2, g2, be2, x2);
    gemm_mfma<1><<<dim3(16, 64), blk, 0, stream>>>(x2, wf1, b_ff1, h, 8192, 2048, 512);
    gemm_mfma<0><<<dim3(4, 64), blk, 0, stream>>>(h, wf2, b_ff2, ff, 8192, 512, 2048);
    ln_kernel<bf16, float, false><<<8192, blk, 0, stream>>>(x2, ff, g3, be3, (float*)d_out);
}

// Round 2
// 337.267 us; speedup vs baseline: 1.0050x; 1.0026x over previous
//
#include <hip/hip_runtime.h>
#include <hip/hip_bf16.h>
#include <math.h>

typedef __hip_bfloat16 bf16;
typedef __attribute__((ext_vector_type(8))) short short8;   // 8 bf16 = 4 VGPRs
typedef __attribute__((ext_vector_type(4))) short s4v;      // 4 bf16 = 8 B
typedef __attribute__((ext_vector_type(4))) float f32x4;    // 16x16 MFMA acc
typedef __attribute__((ext_vector_type(16))) float f32x16;  // 32x32 MFMA acc

__device__ __forceinline__ float ldf(const float* p, size_t i) { return p[i]; }
__device__ __forceinline__ float ldf(const bf16*  p, size_t i) { return __bfloat162float(p[i]); }
__device__ __forceinline__ void  stf(float* p, size_t i, float v) { p[i] = v; }
__device__ __forceinline__ void  stf(bf16*  p, size_t i, float v) { p[i] = __float2bfloat16(v); }

__device__ __forceinline__ float ex2(float x) { return __builtin_amdgcn_exp2f(x); }

// async global->LDS, 16 B per lane; dest = wave-uniform base + lane*16 (m97/m104)
__device__ __forceinline__ void gl16(const void* gp, void* lp) {
    __builtin_amdgcn_global_load_lds(
        (const __attribute__((address_space(1))) void*)gp,
        (__attribute__((address_space(3))) void*)lp, 16, 0, 0);
}

// byte offset into a [64][68] bf16 LDS tile with 16B-granule XOR swizzle:
// granule g of row r stored at slot g^(r&7). All accesses b64 (8B-aligned).
// Read banks: 2r + 4*(g^(r&7)) (+2j) mod 32  ->  ~2-way (free, m136).
__device__ __forceinline__ int lof(int row, int bo) {
    return row * 136 + (((bo >> 4) ^ (row & 7)) << 4) + (bo & 15);
}

// v_permlane32_swap_b32: a' = {a.lo32lanes, b.lo32lanes}, b' = {a.hi, b.hi}
__device__ __forceinline__ void pl32swap(unsigned &a, unsigned &b) {
    asm volatile("v_permlane32_swap_b32 %0, %1" : "+v"(a), "+v"(b));
}

// ---------------------------------------------------------------------------
// fp32 -> bf16 convert (grid-stride)
// ---------------------------------------------------------------------------
__global__ __launch_bounds__(256) void cvt_kernel(
    const float* __restrict__ src, bf16* __restrict__ dst, int n)
{
    for (int i = blockIdx.x * 256 + threadIdx.x; i < n; i += gridDim.x * 256)
        dst[i] = __float2bfloat16(src[i]);
}

// all 6 weight matrices -> one contiguous bf16 region (4,194,304 elems)
__global__ __launch_bounds__(256) void cvt_w(
    const float* __restrict__ s0, const float* __restrict__ s1,
    const float* __restrict__ s2, const float* __restrict__ s3,
    const float* __restrict__ s4, const float* __restrict__ s5,
    bf16* __restrict__ dst)
{
    int i = blockIdx.x * 256 + threadIdx.x;
    const float* s; int off;
    if      (i <  786432) { s = s0; off = 0; }
    else if (i < 1048576) { s = s1; off =  786432; }
    else if (i < 1835008) { s = s2; off = 1048576; }
    else if (i < 2097152) { s = s3; off = 1835008; }
    else if (i < 3145728) { s = s4; off = 2097152; }
    else                  { s = s5; off = 3145728; }
    dst[i] = __float2bfloat16(s[i - off]);
}

// ---------------------------------------------------------------------------
// MFMA GEMM: BM=BN=128, BK=64, XOR-swizzled LDS (group g at g^(row&7)) +
// double-buffered async global_load_lds prefetch. 4 waves (2x2), 64x64/wave.
// C[M,N] = act(A[M,K] @ W[N,K]^T + bias[N]); EPI: 0=none, 1=exact GELU.
// ---------------------------------------------------------------------------
template <int EPI>
__global__ __launch_bounds__(256) void gemm_mfma(
    const bf16* __restrict__ A, const bf16* __restrict__ W,
    const float* __restrict__ bias, bf16* __restrict__ C,
    int M, int N, int K)
{
    __shared__ __align__(16) bf16 Asl[2][128 * 64];
    __shared__ __align__(16) bf16 Bsl[2][128 * 64];

    const int tid  = threadIdx.x;
    const int lane = tid & 63;
    const int wave = tid >> 6;
    const int wm   = wave >> 1;
    const int wn   = wave & 1;
    const int l15  = lane & 15;
    const int quad = lane >> 4;
    const int sr   = lane >> 3;                 // staging row within 8
    const int sc   = ((lane & 7) ^ sr) * 8;     // swizzled source column

    const int row0 = blockIdx.y * 128, col0 = blockIdx.x * 128;

    f32x4 acc[4][4] = {};

    const int nk = K >> 6;

    // prologue: stage tile 0 -> buf 0
    #pragma unroll
    for (int t = 0; t < 4; t++) {
        int r0 = wave * 32 + t * 8;             // wave-uniform, multiple of 8
        gl16(&A[(size_t)(row0 + r0 + sr) * K + sc], &Asl[0][r0 * 64]);
        gl16(&W[(size_t)(col0 + r0 + sr) * K + sc], &Bsl[0][r0 * 64]);
    }

    int cur = 0;
    for (int i = 0; i < nk; i++) {
        __syncthreads();   // drains vmcnt for buf[cur]; prior reads of buf[cur^1] done
        if (i + 1 < nk) {
            int k1 = (i + 1) << 6;
            #pragma unroll
            for (int t = 0; t < 4; t++) {
                int r0 = wave * 32 + t * 8;
                gl16(&A[(size_t)(row0 + r0 + sr) * K + k1 + sc], &Asl[cur ^ 1][r0 * 64]);
                gl16(&W[(size_t)(col0 + r0 + sr) * K + k1 + sc], &Bsl[cur ^ 1][r0 * 64]);
            }
        }

        #pragma unroll
        for (int ks = 0; ks < 64; ks += 32) {
            short8 af[4], bfr[4];
            const int g0 = (ks >> 3) + quad;
            const int col = (g0 ^ (l15 & 7)) * 8;   // un-swizzle on read
            #pragma unroll
            for (int mt = 0; mt < 4; mt++)
                af[mt] = *(const short8*)&Asl[cur][(wm * 64 + mt * 16 + l15) * 64 + col];
            #pragma unroll
            for (int nt = 0; nt < 4; nt++)
                bfr[nt] = *(const short8*)&Bsl[cur][(wn * 64 + nt * 16 + l15) * 64 + col];
            #pragma unroll
            for (int mt = 0; mt < 4; mt++)
                #pragma unroll
                for (int nt = 0; nt < 4; nt++)
                    acc[mt][nt] = __builtin_amdgcn_mfma_f32_16x16x32_bf16(
                        af[mt], bfr[nt], acc[mt][nt], 0, 0, 0);
        }
        cur ^= 1;
    }

    #pragma unroll
    for (int mt = 0; mt < 4; mt++) {
        int row = row0 + wm * 64 + mt * 16 + quad * 4;
        #pragma unroll
        for (int nt = 0; nt < 4; nt++) {
            int col = col0 + wn * 64 + nt * 16 + l15;
            float bv = bias[col];
            #pragma unroll
            for (int r = 0; r < 4; r++) {
                float v = acc[mt][nt][r] + bv;
                if (EPI == 1) v = 0.5f * v * (1.0f + erff(v * 0.70710678118654752f));
                C[(size_t)(row + r) * N + col] = __float2bfloat16(v);
            }
        }
    }
}

// ---------------------------------------------------------------------------
// MFMA flash attention v3 (LDS-traffic-focused rework, m214-style):
//  - 32x32x16 MFMA, 32 q-rows/wave, 2-wave blocks (128 thr, 64 q/block)
//  - swapped QK^T (S^T = K@Q^T): softmax k-axis is lane-local; row reduce =
//    local chain + one shfl_xor(32)
//  - P never touches LDS: v_cvt_pk_bf16_f32 pairs + v_permlane32_swap_b32
//    rebuild the PV A-fragment in registers (T12)
//  - K and V^T tiles in LDS at stride 68 with 16B-granule XOR swizzle,
//    all accesses b64 -> ~2-way banks (free) vs 8-way before
//  - T14 reg-staging (load next tile's K/V to regs during compute)
//  - defer-rescale THR=8 (log2 domain); alpha broadcast via tiny LDS only
//    when it fires
//  - bijective XCD-chunked swizzle keeps each (b,h)'s K/V on one XCD's L2
// LQB: log2(q-blocks per (b,h)); S = 64<<LQB; grid = (8<<LQB)*8 blocks.
// ---------------------------------------------------------------------------
template <int LQB>
__global__ __launch_bounds__(128) void flash_attn_mfma(
    const bf16* __restrict__ qkv, bf16* __restrict__ o)
{
    constexpr int S  = 64 << LQB;
    constexpr int nt = 1 << LQB;

    __shared__ __align__(16) bf16 Kl[64 * 68];
    __shared__ __align__(16) bf16 Vt[64 * 68];
    __shared__ float aB[2][32];

    const int tid  = threadIdx.x;
    const int wave = tid >> 6, lane = tid & 63;
    const int l31  = lane & 31, hi = lane >> 5;

    const int r    = blockIdx.x;
    const int w    = (r & 7) * ((1 << LQB) * 8) + (r >> 3);
    const int qblk = w & ((1 << LQB) - 1);
    const int bh   = w >> LQB;
    const int h    = bh & 7, bb = bh >> 3;
    const int q0   = qblk * 64 + wave * 32;

    const bf16* base = qkv + (size_t)bb * S * 1536 + h * 64;
    char* Kb = (char*)Kl;
    char* Vb = (char*)Vt;

    // Q fragments: lane(q=l31, hi) holds Q[q][c*16 + hi*8 + e]  (B-frag)
    short8 qf[4];
    #pragma unroll
    for (int c = 0; c < 4; c++)
        qf[c] = *(const short8*)&base[(size_t)(q0 + l31) * 1536 + c * 16 + hi * 8];

    f32x16 oacc[2] = {};
    float m2 = -3.0e38f, lrow = 0.f;
    const float CE = 0.18033688f;   // 0.125 * log2(e)

    // staging assignments (128 threads)
    const int kr  = tid >> 1, kh = tid & 1;            // K: row, 32-elem half
    const int vc0 = (tid & 15) * 4, vr8 = (tid >> 4) * 8;  // V: 4 cols x 8 rows

    short8 kst[4];
    s4v    vst[8];

    auto LOADKV = [&](int k0) {
        #pragma unroll
        for (int i = 0; i < 4; i++)
            kst[i] = *(const short8*)&base[(size_t)(k0 + kr) * 1536 + 512 + kh * 32 + i * 8];
        #pragma unroll
        for (int i = 0; i < 8; i++)
            vst[i] = *(const s4v*)&base[(size_t)(k0 + vr8 + i) * 1536 + 1024 + vc0];
    };

    auto WRITEKV = [&]() {
        #pragma unroll
        for (int i = 0; i < 4; i++) {
            int off = lof(kr, kh * 64 + i * 16);
            *(long*)(Kb + off)     = ((const long*)&kst[i])[0];
            *(long*)(Kb + off + 8) = ((const long*)&kst[i])[1];
        }
        // Vt[d][k]: transpose-pack 8 k-rows for each of 4 d-cols
        #pragma unroll
        for (int i = 0; i < 4; i++) {
            union { bf16 b[8]; long l[2]; } pk;
            #pragma unroll
            for (int j = 0; j < 8; j++) pk.b[j] = ((const bf16*)&vst[j])[i];
            int off = lof(vc0 + i, vr8 * 2);
            *(long*)(Vb + off)     = pk.l[0];
            *(long*)(Vb + off + 8) = pk.l[1];
        }
    };

    LOADKV(0);
    for (int it = 0; it < nt; it++) {
        __syncthreads();                 // everyone done reading Kl/Vt
        WRITEKV();                       // waits vmcnt for kst/vst
        __syncthreads();                 // tile visible
        if (it + 1 < nt) LOADKV((it + 1) << 6);   // overlaps compute

        #pragma unroll
        for (int sub = 0; sub < 2; sub++) {
            // S^T = K @ Q^T  (32k x 32q); lane(l31=q,hi): k=(r&3)+8*(r>>2)+4*hi
            f32x16 st = {};
            #pragma unroll
            for (int c = 0; c < 4; c++) {
                union { long l[2]; short8 s; } af;
                int off = lof(sub * 32 + l31, c * 32 + hi * 16);
                af.l[0] = *(const long*)(Kb + off);
                af.l[1] = *(const long*)(Kb + off + 8);
                st = __builtin_amdgcn_mfma_f32_32x32x16_bf16(af.s, qf[c], st, 0, 0, 0);
            }

            // row max: local 16 + cross-half
            float cm = st[0];
            #pragma unroll
            for (int r2 = 1; r2 < 16; r2++) cm = fmaxf(cm, st[r2]);
            cm = fmaxf(cm, __shfl_xor(cm, 32));
            float cm2 = cm * CE;

            // defer-rescale: only pay O-rescale when max grew by > 8 (log2)
            if (__any(cm2 > m2 + 8.f)) {
                float mn2 = fmaxf(m2, cm2);
                float alpha = ex2(m2 - mn2);
                m2 = mn2; lrow *= alpha;
                if (hi == 0) aB[wave][l31] = alpha;
                #pragma unroll
                for (int r2 = 0; r2 < 16; r2++) {
                    float av = aB[wave][(r2 & 3) + 8 * (r2 >> 2) + 4 * hi];
                    oacc[0][r2] *= av; oacc[1][r2] *= av;
                }
            }

            // P = exp2(st*CE - m2), sum
            float p[16]; float ps = 0.f;
            #pragma unroll
            for (int r2 = 0; r2 < 16; r2++) { p[r2] = ex2(st[r2] * CE - m2); ps += p[r2]; }
            ps += __shfl_xor(ps, 32);
            lrow += ps;

            // pack P to bf16 pairs: wk[j] = pack(p[2j], p[2j+1])
            unsigned wk[8];
            #pragma unroll
            for (int j = 0; j < 8; j++)
                asm("v_cvt_pk_bf16_f32 %0, %1, %2" : "=v"(wk[j]) : "v"(p[2*j]), "v"(p[2*j+1]));

            // PV: A-frag via permlane32_swap (zero LDS), B-frag from Vt
            #pragma unroll
            for (int kk = 0; kk < 2; kk++) {
                pl32swap(wk[kk*4+0], wk[kk*4+2]);
                pl32swap(wk[kk*4+1], wk[kk*4+3]);
                union { unsigned u[4]; short8 s; } pa;
                pa.u[0] = wk[kk*4+0]; pa.u[1] = wk[kk*4+1];
                pa.u[2] = wk[kk*4+2]; pa.u[3] = wk[kk*4+3];
                #pragma unroll
                for (int dt = 0; dt < 2; dt++) {
                    union { long l[2]; short8 s; } vf;
                    int off = lof(dt * 32 + l31, sub * 64 + kk * 32 + hi * 16);
                    vf.l[0] = *(const long*)(Vb + off);
                    vf.l[1] = *(const long*)(Vb + off + 8);
                    oacc[dt] = __builtin_amdgcn_mfma_f32_32x32x16_bf16(pa.s, vf.s, oacc[dt], 0, 0, 0);
                }
            }
        }
    }

    // epilogue: normalize and store; O[q][d]: lane(l31=d-col), q=(r&3)+8*(r>>2)+4*hi
    if (hi == 0) aB[wave][l31] = 1.0f / lrow;
    #pragma unroll
    for (int r2 = 0; r2 < 16; r2++) {
        int qr = (r2 & 3) + 8 * (r2 >> 2) + 4 * hi;
        float iv = aB[wave][qr];
        size_t rb = ((size_t)bb * S + q0 + qr) * 512 + h * 64;
        o[rb + l31]      = __float2bfloat16(oacc[0][r2] * iv);
        o[rb + 32 + l31] = __float2bfloat16(oacc[1][r2] * iv);
    }
}

// ---------------------------------------------------------------------------
// out = LN(a + b) * g + beta over D=512. One block (256 thr) per row.
// ---------------------------------------------------------------------------
template <typename AT, typename OT, bool INTERP>
__global__ __launch_bounds__(256) void ln_kernel(
    const AT* __restrict__ a, const bf16* __restrict__ bsrc,
    const float* __restrict__ g, const float* __restrict__ beta,
    OT* __restrict__ out)
{
    const int row = blockIdx.x;
    const int t = threadIdx.x;
    const size_t base = (size_t)row * 512;

    float a0 = ldf(a, base + t), a1 = ldf(a, base + t + 256);
    float b0, b1;
    if (INTERP) {
        int s = row & 1023, bb = row >> 10;
        float src = fminf(fmaxf((s + 0.5f) * 0.5f - 0.5f, 0.f), 511.f);
        int i0 = (int)src;
        int i1 = min(i0 + 1, 511);
        float w = src - (float)i0;
        size_t r0 = ((size_t)bb * 512 + i0) * 512;
        size_t r1 = ((size_t)bb * 512 + i1) * 512;
        b0 = __bfloat162float(bsrc[r0 + t]) * (1.f - w) + __bfloat162float(bsrc[r1 + t]) * w;
        b1 = __bfloat162float(bsrc[r0 + t + 256]) * (1.f - w) + __bfloat162float(bsrc[r1 + t + 256]) * w;
    } else {
        b0 = __bfloat162float(bsrc[base + t]);
        b1 = __bfloat162float(bsrc[base + t + 256]);
    }
    float v0 = a0 + b0, v1 = a1 + b1;

    __shared__ float red[4];
    const int lane = t & 63, wid = t >> 6;

    float sm = v0 + v1;
    #pragma unroll
    for (int off = 32; off > 0; off >>= 1) sm += __shfl_xor(sm, off);
    if (lane == 0) red[wid] = sm;
    __syncthreads();
    sm = red[0] + red[1] + red[2] + red[3];
    const float mean = sm * (1.0f / 512.0f);

    float d0 = v0 - mean, d1 = v1 - mean;
    float vv = d0 * d0 + d1 * d1;
    __syncthreads();
    #pragma unroll
    for (int off = 32; off > 0; off >>= 1) vv += __shfl_xor(vv, off);
    if (lane == 0) red[wid] = vv;
    __syncthreads();
    vv = red[0] + red[1] + red[2] + red[3];
    const float rstd = rsqrtf(vv * (1.0f / 512.0f) + 1e-5f);

    stf(out, base + t,       d0 * rstd * g[t]       + beta[t]);
    stf(out, base + t + 256, d1 * rstd * g[t + 256] + beta[t + 256]);
}

// ---------------------------------------------------------------------------
// avg_pool1d k=2 s=2 along S: [B,1024,512] -> [B,512,512]  (bf16)
// ---------------------------------------------------------------------------
__global__ __launch_bounds__(256) void pool_kernel(
    const bf16* __restrict__ x, bf16* __restrict__ p)
{
    size_t i = (size_t)blockIdx.x * 256 + threadIdx.x;
    size_t d = i & 511;
    size_t rs = i >> 9;
    size_t b = rs >> 9, s = rs & 511;
    size_t r = (b * 1024 + 2 * s) * 512 + d;
    p[i] = __float2bfloat16(0.5f * (__bfloat162float(x[r]) + __bfloat162float(x[r + 512])));
}

// ---------------------------------------------------------------------------
// launch
// ---------------------------------------------------------------------------
extern "C" void kernel_launch(void* const* d_in, const int* in_sizes, int n_in,
                              void* d_out, int out_size, void* d_ws, size_t ws_size,
                              hipStream_t stream)
{
    const float* x      = (const float*)d_in[0];
    const float* w_in1  = (const float*)d_in[1];
    const float* b_in1  = (const float*)d_in[2];
    const float* w_out1 = (const float*)d_in[3];
    const float* b_out1 = (const float*)d_in[4];
    const float* w_in2  = (const float*)d_in[5];
    const float* b_in2  = (const float*)d_in[6];
    const float* w_out2 = (const float*)d_in[7];
    const float* b_out2 = (const float*)d_in[8];
    const float* g1     = (const float*)d_in[9];
    const float* be1    = (const float*)d_in[10];
    const float* g2     = (const float*)d_in[11];
    const float* be2    = (const float*)d_in[12];
    const float* g3     = (const float*)d_in[13];
    const float* be3    = (const float*)d_in[14];
    const float* w_ff1  = (const float*)d_in[15];
    const float* b_ff1  = (const float*)d_in[16];
    const float* w_ff2  = (const float*)d_in[17];
    const float* b_ff2  = (const float*)d_in[18];

    // workspace: bf16 elements; peak 50,331,648 elems = 100.66 MB (proven size)
    bf16* ws     = (bf16*)d_ws;
    bf16* xb     = ws + 0;            // [8,1024, 512]
    bf16* wq1    = ws + 4194304;      // [1536,512]   -- weights contiguous:
    bf16* wo1    = ws + 4980736;      // [512,512]
    bf16* wq2    = ws + 5242880;      // [1536,512]
    bf16* wo2    = ws + 6029312;      // [512,512]
    bf16* wf1    = ws + 6291456;      // [2048,512]
    bf16* wf2    = ws + 7340032;      // [512,2048]
    bf16* qkv1   = ws + 8388608;      // [8,1024,1536]
    bf16* o1     = ws + 20971520;     // [8,1024, 512]
    bf16* a1     = ws + 25165824;     // [8,1024, 512]
    bf16* x1     = ws + 29360128;     // [8,1024, 512]
    bf16* pooled = ws + 33554432;     // [8, 512, 512]
    bf16* qkv2   = ws + 35651584;     // [8, 512,1536]
    bf16* o2     = ws + 41943040;     // [8, 512, 512]
    bf16* a2     = ws + 44040192;     // [8, 512, 512]
    bf16* x2     = ws + 46137344;     // [8,1024, 512]
    bf16* h      = ws + 8388608;      // [8,1024,2048] (qkv1/o1 dead)
    bf16* ff     = ws + 25165824;     // [8,1024, 512] (a1 dead)

    dim3 blk(256);
    dim3 fblk(128);

    cvt_kernel<<<4096, blk, 0, stream>>>(x, xb, 4194304);
    cvt_w<<<16384, blk, 0, stream>>>(w_in1, w_out1, w_in2, w_out2, w_ff1, w_ff2, wq1);

    gemm_mfma<0><<<dim3(12, 64), blk, 0, stream>>>(xb, wq1, b_in1, qkv1, 8192, 1536, 512);
    flash_attn_mfma<4><<<dim3(1024), fblk, 0, stream>>>(qkv1, o1);
    gemm_mfma<0><<<dim3(4, 64), blk, 0, stream>>>(o1, wo1, b_out1, a1, 8192, 512, 512);
    ln_kernel<float, bf16, false><<<8192, blk, 0, stream>>>(x, a1, g1, be1, x1);
    pool_kernel<<<8192, blk, 0, stream>>>(x1, pooled);
    gemm_mfma<0><<<dim3(12, 32), blk, 0, stream>>>(pooled, wq2, b_in2, qkv2, 4096, 1536, 512);
    flash_attn_mfma<3><<<dim3(512), fblk, 0, stream>>>(qkv2, o2);
    gemm_mfma<0><<<dim3(4, 32), blk, 0, stream>>>(o2, wo2, b_out2, a2, 4096, 512, 512);
    ln_kernel<bf16, bf16, true><<<8192, blk, 0, stream>>>(x1, a2, g2, be2, x2);
    gemm_mfma<1><<<dim3(16, 64), blk, 0, stream>>>(x2, wf1, b_ff1, h, 8192, 2048, 512);
    gemm_mfma<0><<<dim3(4, 64), blk, 0, stream>>>(h, wf2, b_ff2, ff, 8192, 512, 2048);
    ln_kernel<bf16, float, false><<<8192, blk, 0, stream>>>(x2, ff, g3, be3, (float*)d_out);
}